// Round 1
// baseline (68.637 us; speedup 1.0000x reference)
//
#include <hip/hip_runtime.h>

// SPU activation bound propagation (RIAI SPUTrainable), collapsed to elementwise.
//
// Reference structure: nal/nau are (n x n+1) matrices with ONLY a diagonal entry
// (lw/uw at column i+1) and a bias (lb/ub at column 0). _substitute with
// yp/yn = l/u column vectors therefore reduces to:
//   al = max(lw,0)*l + min(lw,0)*u + lb
//   au = max(uw,0)*u + min(uw,0)*l + ub
// Output layout: stack([al,au], -1) -> interleaved (al,au) per element.

__device__ __forceinline__ float spu_f(float x) {
    // x>=0: x^2-0.5 ; x<0: sigmoid(-x)-1 = 1/(1+exp(x)) - 1
    if (x >= 0.0f) return x * x - 0.5f;
    return 1.0f / (1.0f + expf(x)) - 1.0f;
}

__device__ __forceinline__ float spu_grad_f(float x) {
    // where(x<=-50, 0, where(x>=0, 2x, -0.5/(cosh(x)+1)))
    if (x <= -50.0f) return 0.0f;
    if (x >= 0.0f) return 2.0f * x;
    return -0.5f / (coshf(x) + 1.0f);
}

__global__ void __launch_bounds__(256)
spu_bounds_kernel(const float* __restrict__ lp, const float* __restrict__ up,
                  const float* __restrict__ tlr, const float* __restrict__ tur,
                  float2* __restrict__ out, int n) {
    int i = blockIdx.x * blockDim.x + threadIdx.x;
    if (i >= n) return;

    float l  = lp[i];
    float u  = up[i];
    float tl = 1.0f / (1.0f + expf(-4.0f * tlr[i]));
    float tu = 1.0f / (1.0f + expf(-4.0f * tur[i]));

    // endpoint (secant) line
    float yl = spu_f(l), yu = spu_f(u);
    float ea = (yu - yl) / (u - l + 1e-8f);
    float eb = yl - l * ea;

    float lw, lb, uw, ub;

    if (u <= 0.0f) {
        // negative branch: lower = secant, upper = tangent at l+(u-l)*tu
        lw = ea; lb = eb;
        float c = l * (1.0f - tu) + u * tu;
        float a = spu_grad_f(c);
        uw = a;
        ub = spu_f(c) - a * c;
    } else if (l >= 0.0f) {
        // positive branch: upper = secant, lower = tangent at l+(u-l)*tl
        float c = l * (1.0f - tl) + u * tl;
        float a = 2.0f * c;             // c >= 0 -> grad = 2c
        lw = a;
        lb = spu_f(c) - a * c;
        uw = ea; ub = eb;
    } else {
        // crossing branch: l < 0 < u
        // --- upper bound: bisect for leftmost tangent point covering (u, spu(u))
        float req = u * u - 0.5f;       // spu(u), u > 0
        float bl = l, br = 0.0f;
        #pragma unroll
        for (int it = 0; it < 20; ++it) {
            float c = 0.5f * (bl + br);
            float a = spu_grad_f(c);
            float b = spu_f(c) - a * c;
            bool covers = (a * u + b >= req);
            bl = covers ? c : bl;
            br = covers ? br : c;
        }
        float c  = l * (1.0f - tu) + bl * tu;
        float ua = spu_grad_f(c);
        float ub_ = spu_f(c) - ua * c;
        bool not_cov = (ua * u + ub_ <= req);   // spu(uc) == req here
        uw = not_cov ? ea : ua;
        ub = not_cov ? eb : ub_;

        // --- lower bound
        float den = u - l;                       // > 0 for crossing
        float threshold = -l / den;              // in (0,1)
        if (tl >= threshold) {
            float cl = l * (1.0f - tl) + u * tl;
            float a2 = spu_grad_f(cl);
            lw = a2;
            lb = spu_f(cl) - a2 * cl;
        } else {
            bool nrm = (l <= -1e-5f) || (l > 0.0f);
            float steep = nrm ? (spu_f(l) + 0.5f) / l : -0.25f;
            float r = tl / threshold;            // threshold > 0 in this branch
            lw = steep * (1.0f - r * r);
            lb = -0.5f;
        }
    }

    float al = fmaxf(lw, 0.0f) * l + fminf(lw, 0.0f) * u + lb;
    float au = fmaxf(uw, 0.0f) * u + fminf(uw, 0.0f) * l + ub;
    out[i] = make_float2(al, au);
}

extern "C" void kernel_launch(void* const* d_in, const int* in_sizes, int n_in,
                              void* d_out, int out_size, void* d_ws, size_t ws_size,
                              hipStream_t stream) {
    const float* l   = (const float*)d_in[0];
    const float* u   = (const float*)d_in[1];
    const float* tlr = (const float*)d_in[2];
    const float* tur = (const float*)d_in[3];
    float2* out = (float2*)d_out;
    int n = in_sizes[0];                 // 64*1024 = 65536 elements
    int block = 256;
    int grid = (n + block - 1) / block;
    spu_bounds_kernel<<<grid, block, 0, stream>>>(l, u, tlr, tur, out, n);
}

// Round 2
// 60.381 us; speedup vs baseline: 1.1367x; 1.1367x over previous
//
#include <hip/hip_runtime.h>

// SPU activation bound propagation (RIAI SPUTrainable), collapsed to elementwise.
//
// nal/nau are diagonal+bias matrices, so _substitute reduces to:
//   al = max(lw,0)*l + min(lw,0)*u + lb
//   au = max(uw,0)*u + min(uw,0)*l + ub
// Output: interleaved (al,au) per element -> float2 stores.
//
// Fast-math identities used (c < 0, t = e^c):
//   spu(c)  = sigmoid(-c)-1     = -t/(1+t)
//   grad(c) = -0.5/(cosh(c)+1)  = -t/(1+t)^2
// One v_exp_f32 + one v_rcp_f32 per bisection step instead of libm coshf+expf.
// Accuracy budget: threshold 0.655 absolute; these are ~1 ulp approximations.

__device__ __forceinline__ float frcp(float x) { return __builtin_amdgcn_rcpf(x); }

__device__ __forceinline__ float spu_fast(float x) {
    if (x >= 0.0f) return x * x - 0.5f;
    float t = __expf(x);
    return -t * frcp(1.0f + t);
}

__device__ __forceinline__ float spu_grad_fast(float x) {
    // where(x<=-50, 0, where(x>=0, 2x, -t/(1+t)^2)); t=e^x underflows to 0 for
    // x<=-50 anyway (|x|<~8 in this problem), so the exp form covers it.
    if (x >= 0.0f) return 2.0f * x;
    float t = __expf(x);
    float inv = frcp(1.0f + t);
    return -t * inv * inv;
}

__global__ void __launch_bounds__(256)
spu_bounds_kernel(const float* __restrict__ lp, const float* __restrict__ up,
                  const float* __restrict__ tlr, const float* __restrict__ tur,
                  float2* __restrict__ out, int n) {
    int i = blockIdx.x * blockDim.x + threadIdx.x;
    if (i >= n) return;

    float l  = lp[i];
    float u  = up[i];
    // sigmoid(4x) = 1/(1+e^{-4x})
    float tl = frcp(1.0f + __expf(-4.0f * tlr[i]));
    float tu = frcp(1.0f + __expf(-4.0f * tur[i]));

    // endpoint (secant) line
    float yl = spu_fast(l), yu = spu_fast(u);
    float ea = (yu - yl) * frcp(u - l + 1e-8f);
    float eb = yl - l * ea;

    float lw, lb, uw, ub;

    if (u <= 0.0f) {
        // negative branch: lower = secant, upper = tangent at l+(u-l)*tu
        lw = ea; lb = eb;
        float c = l * (1.0f - tu) + u * tu;           // c <= 0
        float a = spu_grad_fast(c);
        uw = a;
        ub = spu_fast(c) - a * c;
    } else if (l >= 0.0f) {
        // positive branch: upper = secant, lower = tangent at l+(u-l)*tl
        float c = l * (1.0f - tl) + u * tl;           // c >= 0
        float a = 2.0f * c;
        lw = a;
        lb = (c * c - 0.5f) - a * c;                  // = -c*c - 0.5
        uw = ea; ub = eb;
    } else {
        // crossing branch: l < 0 < u
        // --- upper: bisect in [l,0] for leftmost tangent covering (u, spu(u)).
        // c = (bl+br)/2 < 0 strictly throughout -> pure exp-form, no branches.
        float req = u * u - 0.5f;                     // spu(u), u > 0
        float bl = l, br = 0.0f;
        #pragma unroll
        for (int it = 0; it < 20; ++it) {
            float c   = 0.5f * (bl + br);
            float t   = __expf(c);
            float inv = frcp(1.0f + t);
            float s   = -t * inv;                     // spu(c)
            float a   = s * inv;                      // grad(c) = -t/(1+t)^2
            float b   = fmaf(-a, c, s);               // intercept
            bool covers = fmaf(a, u, b) >= req;
            bl = covers ? c : bl;
            br = covers ? br : c;
        }
        float c2  = l * (1.0f - tu) + bl * tu;        // < 0 (l<0, bl<0)
        float t2  = __expf(c2);
        float iv2 = frcp(1.0f + t2);
        float s2  = -t2 * iv2;
        float ua  = s2 * iv2;
        float ub_ = fmaf(-ua, c2, s2);
        bool not_cov = fmaf(ua, u, ub_) <= req;
        uw = not_cov ? ea : ua;
        ub = not_cov ? eb : ub_;

        // --- lower bound
        float den = u - l;                            // > 0
        float threshold = -l * frcp(den);             // in (0,1)
        if (tl >= threshold) {
            float cl = l * (1.0f - tl) + u * tl;      // any sign
            float a2 = spu_grad_fast(cl);
            lw = a2;
            lb = spu_fast(cl) - a2 * cl;
        } else {
            bool nrm = (l <= -1e-5f) || (l > 0.0f);
            float steep = nrm ? (spu_fast(l) + 0.5f) * frcp(l) : -0.25f;
            float r = tl * frcp(threshold);
            lw = steep * (1.0f - r * r);
            lb = -0.5f;
        }
    }

    float al = fmaxf(lw, 0.0f) * l + fminf(lw, 0.0f) * u + lb;
    float au = fmaxf(uw, 0.0f) * u + fminf(uw, 0.0f) * l + ub;
    out[i] = make_float2(al, au);
}

extern "C" void kernel_launch(void* const* d_in, const int* in_sizes, int n_in,
                              void* d_out, int out_size, void* d_ws, size_t ws_size,
                              hipStream_t stream) {
    const float* l   = (const float*)d_in[0];
    const float* u   = (const float*)d_in[1];
    const float* tlr = (const float*)d_in[2];
    const float* tur = (const float*)d_in[3];
    float2* out = (float2*)d_out;
    int n = in_sizes[0];                 // 64*1024 = 65536
    int block = 256;
    int grid = (n + block - 1) / block;
    spu_bounds_kernel<<<grid, block, 0, stream>>>(l, u, tlr, tur, out, n);
}